// Round 20
// baseline (90.699 us; speedup 1.0000x reference)
//
#include <hip/hip_runtime.h>
#include <stdint.h>

#define IN_DIM 1024
#define OUT_DIM 1024
#define NROWS 8192

#define BM 256
#define BN 128
#define ICW 32             // i-cols per supertile
#define ICN 32             // supertiles

typedef __bf16 bf16x8 __attribute__((ext_vector_type(8)));
typedef float f32x4 __attribute__((ext_vector_type(4)));
typedef unsigned short us8 __attribute__((ext_vector_type(8)));
typedef unsigned int u32;

#define AS1 __attribute__((address_space(1)))
#define AS3 __attribute__((address_space(3)))

__device__ __forceinline__ unsigned short f2bf(float f) {
    u32 u = __builtin_bit_cast(u32, f);
    u32 r = (u + 0x7fffu + ((u >> 16) & 1u)) >> 16;   // RNE, finite inputs
    return (unsigned short)r;
}

__device__ __forceinline__ bf16x8 ld8(const unsigned short* p) {
    return __builtin_bit_cast(bf16x8, *reinterpret_cast<const us8*>(p));
}

// ---- merged prep:
// blocks [0, 4096):    A1 = bf16(x)  [8192][1024]  (16 MB — p=1 plane only)
// blocks [4096, 5120): coeffs -> bf16 B[OUT_DIM][3072] k-major (k=(p-1)*1024+i),
//                      c0 folded into bias2.  (powers p>=2 derived IN-GEMM)
__global__ __launch_bounds__(256) void taylor_prep(const float* __restrict__ x,
                                                   const float* __restrict__ c,
                                                   const float* __restrict__ bias,
                                                   unsigned short* __restrict__ A1,
                                                   unsigned short* __restrict__ B,
                                                   float* __restrict__ bias2) {
    if (blockIdx.x < 4096) {
        int t = blockIdx.x * 256 + threadIdx.x;     // 8 floats each
        const float4* xp = reinterpret_cast<const float4*>(x) + (size_t)t * 2;
        float4 v0 = xp[0], v1 = xp[1];
        unsigned short o[8] = {f2bf(v0.x), f2bf(v0.y), f2bf(v0.z), f2bf(v0.w),
                               f2bf(v1.x), f2bf(v1.y), f2bf(v1.z), f2bf(v1.w)};
        *reinterpret_cast<uint4*>(A1 + (size_t)t * 8) = *reinterpret_cast<uint4*>(o);
    } else {
        const int o = blockIdx.x - 4096;
        const float4* row = reinterpret_cast<const float4*>(c + (size_t)o * (IN_DIM * 4));
        unsigned short* Bo = B + (size_t)o * 3072;
        float s = 0.f;
        for (int i = threadIdx.x; i < IN_DIM; i += 256) {
            float4 v = row[i];            // {c0, c1, c2, c3}
            s += v.x;
            Bo[i]        = f2bf(v.y);
            Bo[1024 + i] = f2bf(v.z);
            Bo[2048 + i] = f2bf(v.w);
        }
#pragma unroll
        for (int off = 32; off; off >>= 1) s += __shfl_down(s, off);
        __shared__ float red[4];
        if ((threadIdx.x & 63) == 0) red[threadIdx.x >> 6] = s;
        __syncthreads();
        if (threadIdx.x == 0) bias2[o] = bias[o] + red[0] + red[1] + red[2] + red[3];
    }
}

// ---- fused-powers GEMM: C[n][o] = sum_{p,i} x^p * B[o][(p-1)*1024+i] + bias2
// r15 skeleton, but A-LDS holds ONLY bf16(x): x^2, x^3 fragments are derived
// IN-REGISTER (fp32 mul + bf16 round on the idle VALU pipe). Supertile =
// 32 i-cols x {p=1,2,3}: LDS traffic per K-64 drops 176->112 KB, balancing
// LDS (~1976 cyc/supertile) against MFMA (1862). 512 thr / 8 waves 4Mx2N
// (wave 64x64), grid 256 (1/CU), double-buffered LDS (80 KiB), stage-1-ahead
// (vmcnt(0) at top drains units issued a full supertile ago), 3 phases
// (one per power) x 16 MFMA with closing barriers, setprio, rule-#21
// swizzle pair re-derived for 64B rows (2-way max = free).
// Precision: x2=3eps, x3=4eps vs 2eps -> absmax ~0.11 (thr 0.176).
__global__ __launch_bounds__(512, 1) void taylor_gemm(
    const unsigned short* __restrict__ A1,   // bf16 x [8192][1024]
    const unsigned short* __restrict__ B,    // bf16 [1024][3072] k-major
    const float* __restrict__ bias2,
    float* __restrict__ C) {
    __shared__ alignas(16) unsigned short sX[2][BM * ICW];      // 2 x 16 KiB
    __shared__ alignas(16) unsigned short sB[2][3][BN * ICW];   // 2 x 24 KiB

    const int tid = threadIdx.x;
    const int lane = tid & 63;
    const int wid = tid >> 6;       // 0..7
    const int wr = wid >> 1;        // 0..3  (M quarter: 64 rows)
    const int wc = wid & 1;         // 0..1  (N half: 64 cols)
    const int gx = blockIdx.x, gy = blockIdx.y;

    // ---- staging: 5 gld_lds units/wave/supertile (X:2, B:3) ----
    // 64B rows = 4x16B slots. Swizzle involution: LDS slot t of row r holds
    // global slot t ^ (r&3) ^ ((r>>2)&3). Staging lane l covers row
    // rb + (l>>2) (rb 16-aligned), LDS slot l&3 -> pre-swizzled global slot:
    const char* Xb = (const char*)A1;
    const char* Bb = (const char*)B;
    const int gslot = (lane & 3) ^ ((lane >> 2) & 3) ^ ((lane >> 4) & 3);
    size_t xSrc[2], bSrc[3];
    int xDst[2];
#pragma unroll
    for (int u = 0; u < 2; ++u) {
        int row = gx * BM + wid * 32 + u * 16 + (lane >> 2);
        xSrc[u] = ((size_t)row * 1024 + gslot * 8) * 2;
        xDst[u] = (wid * 32 + u * 16) * ICW;
    }
#pragma unroll
    for (int p = 0; p < 3; ++p) {
        int row = gy * BN + wid * 16 + (lane >> 2);
        bSrc[p] = ((size_t)row * 3072 + p * 1024 + gslot * 8) * 2;
    }
    const int bDst = (wid * 16) * ICW;

    auto stage_all = [&](int d, int ic) {
        size_t koff = (size_t)ic * (ICW * 2);
#pragma unroll
        for (int u = 0; u < 2; ++u)
            __builtin_amdgcn_global_load_lds(
                (const AS1 void*)(Xb + xSrc[u] + koff),
                (AS3 void*)(&sX[d][xDst[u]]), 16, 0, 0);
#pragma unroll
        for (int p = 0; p < 3; ++p)
            __builtin_amdgcn_global_load_lds(
                (const AS1 void*)(Bb + bSrc[p] + koff),
                (AS3 void*)(&sB[d][p][bDst]), 16, 0, 0);
    };

    // frag read addrs (ushort idx): row r, slot s = lane>>4, K=32 -> one ks.
    // mask (r&3)^((r>>2)&3) with r = base16 + (lane&15)  ->  lane-only:
    const int msk = (lane & 3) ^ ((lane >> 2) & 3);
    const int swz = ((lane >> 4) ^ msk) * 8;
    int xRd[4], bRd[4];
#pragma unroll
    for (int m = 0; m < 4; ++m)
        xRd[m] = (wr * 64 + m * 16 + (lane & 15)) * ICW + swz;
#pragma unroll
    for (int n = 0; n < 4; ++n)
        bRd[n] = (wc * 64 + n * 16 + (lane & 15)) * ICW + swz;

    f32x4 acc[4][4] = {};

    // prologue: stage supertile 0
    stage_all(0, 0);

    for (int ic = 0; ic < ICN; ++ic) {
        const int d = ic & 1;
        // supertile ic's 5 units were issued one full supertile (~2000cyc) ago
        asm volatile("s_waitcnt vmcnt(0)" ::: "memory");
        __builtin_amdgcn_s_barrier();
        __builtin_amdgcn_sched_barrier(0);
        if (ic + 1 < ICN) stage_all(d ^ 1, ic + 1);
        __builtin_amdgcn_sched_barrier(0);

        // ---- phase 1 (p=1): B1 + x frags -> 16 MFMA; derive x2 under drain ----
        bf16x8 xf[4], b1[4];
#pragma unroll
        for (int n = 0; n < 4; ++n) b1[n] = ld8(&sB[d][0][bRd[n]]);
#pragma unroll
        for (int m = 0; m < 4; ++m) xf[m] = ld8(&sX[d][xRd[m]]);
        asm volatile("s_waitcnt lgkmcnt(0)" ::: "memory");
        __builtin_amdgcn_sched_barrier(0);   // rule #18
        __builtin_amdgcn_s_setprio(1);
#pragma unroll
        for (int m = 0; m < 4; ++m)
#pragma unroll
            for (int n = 0; n < 4; ++n)
                acc[m][n] = __builtin_amdgcn_mfma_f32_16x16x32_bf16(
                    xf[m], b1[n], acc[m][n], 0, 0, 0);
        __builtin_amdgcn_s_setprio(0);
        // derivation overlaps the MFMA cluster's drain (independent of it)
        float xff[4][8];
        bf16x8 x2f[4];
#pragma unroll
        for (int m = 0; m < 4; ++m)
#pragma unroll
            for (int j = 0; j < 8; ++j) {
                float w = (float)xf[m][j];
                xff[m][j] = w;
                x2f[m][j] = (__bf16)(w * w);
            }
        __builtin_amdgcn_s_barrier();
        __builtin_amdgcn_sched_barrier(0);

        // ---- phase 2 (p=2): B2 -> 16 MFMA(x2); derive x3 under drain ----
        bf16x8 b2[4];
#pragma unroll
        for (int n = 0; n < 4; ++n) b2[n] = ld8(&sB[d][1][bRd[n]]);
        asm volatile("s_waitcnt lgkmcnt(0)" ::: "memory");
        __builtin_amdgcn_sched_barrier(0);
        __builtin_amdgcn_s_setprio(1);
#pragma unroll
        for (int m = 0; m < 4; ++m)
#pragma unroll
            for (int n = 0; n < 4; ++n)
                acc[m][n] = __builtin_amdgcn_mfma_f32_16x16x32_bf16(
                    x2f[m], b2[n], acc[m][n], 0, 0, 0);
        __builtin_amdgcn_s_setprio(0);
        bf16x8 x3f[4];
#pragma unroll
        for (int m = 0; m < 4; ++m)
#pragma unroll
            for (int j = 0; j < 8; ++j) {
                float w = xff[m][j];
                x3f[m][j] = (__bf16)(w * w * w);
            }
        __builtin_amdgcn_s_barrier();
        __builtin_amdgcn_sched_barrier(0);

        // ---- phase 3 (p=3): B3 -> 16 MFMA(x3) ----
        bf16x8 b3[4];
#pragma unroll
        for (int n = 0; n < 4; ++n) b3[n] = ld8(&sB[d][2][bRd[n]]);
        asm volatile("s_waitcnt lgkmcnt(0)" ::: "memory");
        __builtin_amdgcn_sched_barrier(0);
        __builtin_amdgcn_s_setprio(1);
#pragma unroll
        for (int m = 0; m < 4; ++m)
#pragma unroll
            for (int n = 0; n < 4; ++n)
                acc[m][n] = __builtin_amdgcn_mfma_f32_16x16x32_bf16(
                    x3f[m], b3[n], acc[m][n], 0, 0, 0);
        __builtin_amdgcn_s_setprio(0);
        __builtin_amdgcn_s_barrier();        // closes supertile (WAR-safe)
        __builtin_amdgcn_sched_barrier(0);
    }

    // epilogue: C/D layout col = lane&15, row = (lane>>4)*4 + r
    const int colBase = gy * BN + wc * 64 + (lane & 15);
    const int rowBase = gx * BM + wr * 64 + (lane >> 4) * 4;
#pragma unroll
    for (int n = 0; n < 4; ++n) {
        int col = colBase + n * 16;
        float bv = bias2[col];
#pragma unroll
        for (int m = 0; m < 4; ++m) {
            int row = rowBase + m * 16;
#pragma unroll
            for (int r = 0; r < 4; ++r)
                C[(size_t)(row + r) * OUT_DIM + col] = acc[m][n][r] + bv;
        }
    }
}

// ---- fallback (ws too small): fp32 LDS-staged, correct but slow ----
__global__ void taylor_naive(const float* __restrict__ x, const float* __restrict__ coeffs,
                             const float* __restrict__ bias, float* __restrict__ out) {
    int n = blockIdx.x;
    __shared__ float P[IN_DIM * 4];
    for (int i = threadIdx.x; i < IN_DIM; i += blockDim.x) {
        float xv = x[(size_t)n * IN_DIM + i];
        P[i * 4 + 0] = 1.f;
        P[i * 4 + 1] = xv;
        P[i * 4 + 2] = xv * xv;
        P[i * 4 + 3] = xv * xv * xv;
    }
    __syncthreads();
    for (int o = threadIdx.x; o < OUT_DIM; o += blockDim.x) {
        float s = bias[o];
        const float* c = coeffs + (size_t)o * (IN_DIM * 4);
        for (int i = 0; i < IN_DIM; ++i) {
            float4 cv = *reinterpret_cast<const float4*>(c + i * 4);
            s += cv.x * P[i * 4 + 0] + cv.y * P[i * 4 + 1] +
                 cv.z * P[i * 4 + 2] + cv.w * P[i * 4 + 3];
        }
        out[(size_t)n * OUT_DIM + o] = s;
    }
}

extern "C" void kernel_launch(void* const* d_in, const int* in_sizes, int n_in,
                              void* d_out, int out_size, void* d_ws, size_t ws_size,
                              hipStream_t stream) {
    const float* x = (const float*)d_in[0];
    const float* coeffs = (const float*)d_in[1];
    const float* bias = (const float*)d_in[2];
    float* out = (float*)d_out;

    const size_t needA = (size_t)NROWS * IN_DIM * 2;    // 16 MiB (bf16 x)
    const size_t needB = (size_t)OUT_DIM * 3072 * 2;    // 6 MiB
    const size_t needBias = OUT_DIM * sizeof(float);    // 4 KiB

    if (ws_size >= needA + needB + needBias) {
        unsigned short* A1 = (unsigned short*)d_ws;
        unsigned short* B = (unsigned short*)((char*)d_ws + needA);
        float* bias2 = (float*)((char*)d_ws + needA + needB);
        taylor_prep<<<4096 + 1024, 256, 0, stream>>>(x, coeffs, bias, A1, B, bias2);
        dim3 grid(NROWS / BM, OUT_DIM / BN);   // (32, 8) = 256 blocks, 1/CU
        taylor_gemm<<<grid, 512, 0, stream>>>(A1, B, bias2, out);
    } else {
        taylor_naive<<<NROWS, 256, 0, stream>>>(x, coeffs, bias, out);
    }
}

// Round 21
// 72.810 us; speedup vs baseline: 1.2457x; 1.2457x over previous
//
#include <hip/hip_runtime.h>
#include <stdint.h>

#define IN_DIM 1024
#define OUT_DIM 1024
#define NROWS 8192
#define KD 3072            // k-major: k = (p-1)*1024 + i, p = 1..3 (k=0 folded into bias)

#define BM 256
#define BN 128
#define BK 64
#define NT (KD / BK)       // 48 K-tiles

typedef __bf16 bf16x8 __attribute__((ext_vector_type(8)));
typedef float f32x4 __attribute__((ext_vector_type(4)));
typedef unsigned short us8 __attribute__((ext_vector_type(8)));
typedef unsigned int u32;

#define AS1 __attribute__((address_space(1)))
#define AS3 __attribute__((address_space(3)))

__device__ __forceinline__ unsigned short f2bf(float f) {
    u32 u = __builtin_bit_cast(u32, f);
    u32 r = (u + 0x7fffu + ((u >> 16) & 1u)) >> 16;   // RNE, finite inputs
    return (unsigned short)r;
}

__device__ __forceinline__ bf16x8 ld8(const unsigned short* p) {
    return __builtin_bit_cast(bf16x8, *reinterpret_cast<const us8*>(p));
}

// ---- merged prep (one dispatch, r13-verified merge pattern):
// blocks [0, 8192):    powers of x -> bf16 A[NROWS][KD] (k-major)
// blocks [8192, 9216): coeffs -> bf16 B[OUT_DIM][KD] (k-major), c0 -> bias2
__global__ __launch_bounds__(256) void taylor_prep(const float* __restrict__ x,
                                                   const float* __restrict__ c,
                                                   const float* __restrict__ bias,
                                                   unsigned short* __restrict__ A,
                                                   unsigned short* __restrict__ B,
                                                   float* __restrict__ bias2) {
    if (blockIdx.x < 8192) {
        int t = blockIdx.x * 256 + threadIdx.x;           // each handles 4 x values
        int n = t >> 8;                                   // 256 float4 per row
        int i4 = (t & 255) * 4;
        float4 v = reinterpret_cast<const float4*>(x)[t];
        unsigned short* An = A + (size_t)n * KD + i4;
        float xs[4] = {v.x, v.y, v.z, v.w};
        unsigned short b1[4], b2[4], b3[4];
#pragma unroll
        for (int j = 0; j < 4; ++j) {
            float x1 = xs[j], x2 = x1 * x1, x3 = x2 * x1;
            b1[j] = f2bf(x1); b2[j] = f2bf(x2); b3[j] = f2bf(x3);
        }
        ushort4 p1 = {b1[0], b1[1], b1[2], b1[3]};
        ushort4 p2 = {b2[0], b2[1], b2[2], b2[3]};
        ushort4 p3 = {b3[0], b3[1], b3[2], b3[3]};
        *reinterpret_cast<ushort4*>(An)        = p1;
        *reinterpret_cast<ushort4*>(An + 1024) = p2;
        *reinterpret_cast<ushort4*>(An + 2048) = p3;
    } else {
        const int o = blockIdx.x - 8192;
        const float4* row = reinterpret_cast<const float4*>(c + (size_t)o * (IN_DIM * 4));
        unsigned short* Bo = B + (size_t)o * KD;
        float s = 0.f;
        for (int i = threadIdx.x; i < IN_DIM; i += 256) {
            float4 v = row[i];            // {c0, c1, c2, c3} for (o, i)
            s += v.x;
            Bo[i]        = f2bf(v.y);
            Bo[1024 + i] = f2bf(v.z);
            Bo[2048 + i] = f2bf(v.w);
        }
#pragma unroll
        for (int off = 32; off; off >>= 1) s += __shfl_down(s, off);
        __shared__ float red[4];
        if ((threadIdx.x & 63) == 0) red[threadIdx.x >> 6] = s;
        __syncthreads();
        if (threadIdx.x == 0) bias2[o] = bias[o] + red[0] + red[1] + red[2] + red[3];
    }
}

// ---- main GEMM: C = A[M][KD] * B[N][KD]^T + bias2 ----
// SESSION-BEST STRUCTURE (r15/r19: 55.2us GEMM, 933 TF, reproduced twice):
// BM=256 BN=128 BK=64, grid 256 (1 block/CU), 512 thr / 8 waves as 4M x 2N
// (wave tile 64x64 — duplication-optimal). Triple-buffered LDS (144 KiB),
// stage-2-ahead with vmcnt(6) counted once per tile (tile kt+1's 6 units
// stay in flight across barriers), 2 phases x 16 MFMA with phase-closing
// barriers, T2 XOR-swizzle pair (SQ_LDS_BANK_CONFLICT=0), setprio on MFMA.
// Verified dead ends (do not revisit): A-direct (r11), B-direct (r14/r18),
// 1 wave/SIMD (r17), fused in-register A-gen (r6-r9), fused-powers with
// 32-col supertiles (r20: bank conflicts + 3x barriers + conv on critical
// path), 2-blocks/CU VGPR cap (r7 spills), cross-half-tile reg pipe (r16
// neutral), 2Mx4N waves (r13: +2us vs 4Mx2N).
__global__ __launch_bounds__(512, 1) void taylor_gemm(
    const unsigned short* __restrict__ A,   // bf16 [NROWS][KD]
    const unsigned short* __restrict__ B,   // bf16 [OUT_DIM][KD]
    const float* __restrict__ bias2,
    float* __restrict__ C) {
    __shared__ alignas(16) unsigned short sA[3][BM * BK];  // 3 x 32 KiB
    __shared__ alignas(16) unsigned short sB[3][BN * BK];  // 3 x 16 KiB

    const int tid = threadIdx.x;
    const int lane = tid & 63;
    const int wid = tid >> 6;       // 0..7
    const int wr = wid >> 1;        // 0..3  (M quarter: 64 rows)
    const int wc = wid & 1;         // 0..1  (N half: 64 cols)
    const int gx = blockIdx.x, gy = blockIdx.y;

    // ---- staging: 6 gld_lds units/wave/tile (A:4, B:2), T2 source swizzle ----
    const char* Ab = (const char*)A;
    const char* Bb = (const char*)B;
    const int cs = ((lane & 7) ^ (lane >> 3)) * 8;   // swizzled source col (ushort)
    size_t aSrc[4], bSrc[2];
    int aDst[4], bDst[2];
#pragma unroll
    for (int u = 0; u < 4; ++u) {
        int row = gx * BM + u * 64 + wid * 8 + (lane >> 3);
        aSrc[u] = ((size_t)row * KD + cs) * 2;
        aDst[u] = (u * 64 + wid * 8) * BK;
    }
#pragma unroll
    for (int u = 0; u < 2; ++u) {
        int row = gy * BN + u * 64 + wid * 8 + (lane >> 3);
        bSrc[u] = ((size_t)row * KD + cs) * 2;
        bDst[u] = (u * 64 + wid * 8) * BK;
    }

    auto stage_unit = [&](int b, int kt, int u) {
        size_t koff = (size_t)kt * (BK * 2);
        if (u < 4)
            __builtin_amdgcn_global_load_lds(
                (const AS1 void*)(Ab + aSrc[u] + koff),
                (AS3 void*)(&sA[b][aDst[u]]), 16, 0, 0);
        else
            __builtin_amdgcn_global_load_lds(
                (const AS1 void*)(Bb + bSrc[u - 4] + koff),
                (AS3 void*)(&sB[b][bDst[u - 4]]), 16, 0, 0);
    };

    // swizzled fragment read bases (ushort index), per ks:
    // A row r = wr*64 + m*16 + (lane&15); B row r = wc*64 + n*16 + (lane&15)
    // (r&7 == lane&7); slot s = ks*4+(lane>>4); addr = r*64 + (s^(lane&7))*8
    int aSw[2], bSw[2];
#pragma unroll
    for (int ks = 0; ks < 2; ++ks) {
        int sw = ((ks * 4 + (lane >> 4)) ^ (lane & 7)) * 8;
        aSw[ks] = (wr * 64 + (lane & 15)) * BK + sw;
        bSw[ks] = (wc * 64 + (lane & 15)) * BK + sw;
    }

    f32x4 acc[4][4] = {};

    // prologue: stage tiles 0,1 -> bufs 0,1 (12 units outstanding/wave)
#pragma unroll
    for (int u = 0; u < 6; ++u) stage_unit(0, 0, u);
#pragma unroll
    for (int u = 0; u < 6; ++u) stage_unit(1, 1, u);

    for (int kt = 0; kt < NT; ++kt) {
        const int cb = kt % 3;
        const int nb = (kt + 2) % 3;
        // counted wait: tile kt's 6 units landed; tile kt+1's 6 stay in flight
        if (kt < NT - 1) asm volatile("s_waitcnt vmcnt(6)" ::: "memory");
        else             asm volatile("s_waitcnt vmcnt(0)" ::: "memory");
        __builtin_amdgcn_s_barrier();        // cross-wave staging visibility
        __builtin_amdgcn_sched_barrier(0);

        const unsigned short* sAc = &sA[cb][0];
        const unsigned short* sBc = &sB[cb][0];
        const bool doStage = (kt < NT - 2);

        // ---- phase 0: B frags (8) + A frags m0,m1 (4) || stage 3 -> 16 MFMA ----
        bf16x8 bf[4][2], af[2][2];
#pragma unroll
        for (int n = 0; n < 4; ++n)
#pragma unroll
            for (int ks = 0; ks < 2; ++ks)
                bf[n][ks] = ld8(&sBc[bSw[ks] + n * 16 * BK]);
#pragma unroll
        for (int mi = 0; mi < 2; ++mi)
#pragma unroll
            for (int ks = 0; ks < 2; ++ks)
                af[mi][ks] = ld8(&sAc[aSw[ks] + mi * 16 * BK]);
        if (doStage) {
            stage_unit(nb, kt + 2, 0);
            stage_unit(nb, kt + 2, 4);
            stage_unit(nb, kt + 2, 1);
        }
        asm volatile("s_waitcnt lgkmcnt(0)" ::: "memory");
        __builtin_amdgcn_sched_barrier(0);   // rule #18
        __builtin_amdgcn_s_setprio(1);
#pragma unroll
        for (int mi = 0; mi < 2; ++mi)
#pragma unroll
            for (int n = 0; n < 4; ++n)
#pragma unroll
                for (int ks = 0; ks < 2; ++ks)
                    acc[mi][n] = __builtin_amdgcn_mfma_f32_16x16x32_bf16(
                        af[mi][ks], bf[n][ks], acc[mi][n], 0, 0, 0);
        __builtin_amdgcn_s_setprio(0);
        __builtin_amdgcn_s_barrier();        // phase-closing barrier (role split)
        __builtin_amdgcn_sched_barrier(0);

        // ---- phase 1: A frags m2,m3 (4) || stage 3 -> 16 MFMA ----
        bf16x8 af2[2][2];
#pragma unroll
        for (int mi = 0; mi < 2; ++mi)
#pragma unroll
            for (int ks = 0; ks < 2; ++ks)
                af2[mi][ks] = ld8(&sAc[aSw[ks] + (2 + mi) * 16 * BK]);
        if (doStage) {
            stage_unit(nb, kt + 2, 5);
            stage_unit(nb, kt + 2, 2);
            stage_unit(nb, kt + 2, 3);
        }
        asm volatile("s_waitcnt lgkmcnt(0)" ::: "memory");
        __builtin_amdgcn_sched_barrier(0);
        __builtin_amdgcn_s_setprio(1);
#pragma unroll
        for (int mi = 0; mi < 2; ++mi)
#pragma unroll
            for (int n = 0; n < 4; ++n)
#pragma unroll
                for (int ks = 0; ks < 2; ++ks)
                    acc[2 + mi][n] = __builtin_amdgcn_mfma_f32_16x16x32_bf16(
                        af2[mi][ks], bf[n][ks], acc[2 + mi][n], 0, 0, 0);
        __builtin_amdgcn_s_setprio(0);
        __builtin_amdgcn_s_barrier();        // phase-closing barrier
        __builtin_amdgcn_sched_barrier(0);
    }

    // epilogue: C/D layout col = lane&15, row = (lane>>4)*4 + r
    const int colBase = gy * BN + wc * 64 + (lane & 15);
    const int rowBase = gx * BM + wr * 64 + (lane >> 4) * 4;
#pragma unroll
    for (int n = 0; n < 4; ++n) {
        int col = colBase + n * 16;
        float bv = bias2[col];
#pragma unroll
        for (int m = 0; m < 4; ++m) {
            int row = rowBase + m * 16;
#pragma unroll
            for (int r = 0; r < 4; ++r)
                C[(size_t)(row + r) * OUT_DIM + col] = acc[m][n][r] + bv;
        }
    }
}

// ---- fallback (ws too small): fp32 LDS-staged, correct but slow ----
__global__ void taylor_naive(const float* __restrict__ x, const float* __restrict__ coeffs,
                             const float* __restrict__ bias, float* __restrict__ out) {
    int n = blockIdx.x;
    __shared__ float P[IN_DIM * 4];
    for (int i = threadIdx.x; i < IN_DIM; i += blockDim.x) {
        float xv = x[(size_t)n * IN_DIM + i];
        P[i * 4 + 0] = 1.f;
        P[i * 4 + 1] = xv;
        P[i * 4 + 2] = xv * xv;
        P[i * 4 + 3] = xv * xv * xv;
    }
    __syncthreads();
    for (int o = threadIdx.x; o < OUT_DIM; o += blockDim.x) {
        float s = bias[o];
        const float* c = coeffs + (size_t)o * (IN_DIM * 4);
        for (int i = 0; i < IN_DIM; ++i) {
            float4 cv = *reinterpret_cast<const float4*>(c + i * 4);
            s += cv.x * P[i * 4 + 0] + cv.y * P[i * 4 + 1] +
                 cv.z * P[i * 4 + 2] + cv.w * P[i * 4 + 3];
        }
        out[(size_t)n * OUT_DIM + o] = s;
    }
}

extern "C" void kernel_launch(void* const* d_in, const int* in_sizes, int n_in,
                              void* d_out, int out_size, void* d_ws, size_t ws_size,
                              hipStream_t stream) {
    const float* x = (const float*)d_in[0];
    const float* coeffs = (const float*)d_in[1];
    const float* bias = (const float*)d_in[2];
    float* out = (float*)d_out;

    const size_t needA = (size_t)NROWS * KD * 2;     // 48 MiB
    const size_t needB = (size_t)OUT_DIM * KD * 2;   // 6 MiB
    const size_t needBias = OUT_DIM * sizeof(float); // 4 KiB

    if (ws_size >= needA + needB + needBias) {
        unsigned short* A = (unsigned short*)d_ws;
        unsigned short* B = (unsigned short*)((char*)d_ws + needA);
        float* bias2 = (float*)((char*)d_ws + needA + needB);
        taylor_prep<<<8192 + 1024, 256, 0, stream>>>(x, coeffs, bias, A, B, bias2);
        dim3 grid(NROWS / BM, OUT_DIM / BN);   // (32, 8) = 256 blocks, 1/CU
        taylor_gemm<<<grid, 512, 0, stream>>>(A, B, bias2, out);
    } else {
        taylor_naive<<<NROWS, 256, 0, stream>>>(x, coeffs, bias, out);
    }
}